// Round 1
// baseline (977.158 us; speedup 1.0000x reference)
//
#include <hip/hip_runtime.h>
#include <math.h>

#define N_NODES 40000
#define N_EDGES 640000
#define D 128
#define D_OUT 64
#define D_CAT 384

// ---------------- degree / normalization ----------------
__global__ void k_deg_init(float* __restrict__ deg) {
    int i = blockIdx.x * blockDim.x + threadIdx.x;
    if (i < N_NODES) deg[i] = 1.0f;  // self-loop
}

__global__ void k_deg_edges(const int* __restrict__ tgt, float* __restrict__ deg) {
    int e = blockIdx.x * blockDim.x + threadIdx.x;
    if (e < N_EDGES) atomicAdd(&deg[tgt[e]], 1.0f);
}

__global__ void k_dis(float* __restrict__ deg) {
    int i = blockIdx.x * blockDim.x + threadIdx.x;
    if (i < N_NODES) deg[i] = rsqrtf(deg[i]);
}

// ---------------- GEMM: H = X @ W   (X: [N,128], W: [128,128]) ----------------
__global__ __launch_bounds__(256) void k_gemm128(const float* __restrict__ X,
                                                 const float* __restrict__ W,
                                                 float* __restrict__ H) {
    __shared__ float Ws[128 * 128];   // 64 KB
    __shared__ float Xs[2][128];
    for (int i = threadIdx.x; i < 128 * 128; i += 256) Ws[i] = W[i];
    __syncthreads();

    int rs = threadIdx.x >> 7;   // 0..1 : which of the 2 rows
    int cj = threadIdx.x & 127;  // output column

    for (int row0 = blockIdx.x * 2; row0 < N_NODES; row0 += gridDim.x * 2) {
        int r = row0 + rs;
        if (r < N_NODES) Xs[rs][cj] = X[(size_t)r * D + cj];
        __syncthreads();
        if (r < N_NODES) {
            float acc = 0.0f;
            #pragma unroll 8
            for (int k = 0; k < 128; ++k)
                acc = fmaf(Xs[rs][k], Ws[k * 128 + cj], acc);
            H[(size_t)r * D + cj] = acc;
        }
        __syncthreads();
    }
}

// ---------------- aggregation ----------------
// agg[i][d] = b[d] + dis[i]^2 * h[i][d]   (bias + self-loop term)
__global__ void k_agg_init(const float* __restrict__ H, const float* __restrict__ dis,
                           const float* __restrict__ b, float* __restrict__ AGG) {
    int i = blockIdx.x * blockDim.x + threadIdx.x;  // over N*D/4 float4s
    if (i >= N_NODES * D / 4) return;
    int row = i / (D / 4);
    int d4  = i % (D / 4);
    float s = dis[row];
    float c = s * s;
    const float4 h4 = ((const float4*)H)[i];
    const float4 b4 = ((const float4*)b)[d4];
    float4 o;
    o.x = b4.x + c * h4.x;
    o.y = b4.y + c * h4.y;
    o.z = b4.z + c * h4.z;
    o.w = b4.w + c * h4.w;
    ((float4*)AGG)[i] = o;
}

// one wave per edge (grid-stride): AGG[tgt] += dis[t]*dis[s] * H[src]
__global__ __launch_bounds__(256) void k_agg_edges(const int* __restrict__ tgt,
                                                   const int* __restrict__ src,
                                                   const float* __restrict__ dis,
                                                   const float* __restrict__ H,
                                                   float* __restrict__ AGG) {
    int wave  = (blockIdx.x * blockDim.x + threadIdx.x) >> 6;
    int lane  = threadIdx.x & 63;
    int nwave = (gridDim.x * blockDim.x) >> 6;
    for (int e = wave; e < N_EDGES; e += nwave) {
        int t = tgt[e];
        int s = src[e];
        float coef = dis[t] * dis[s];
        float v0 = H[(size_t)s * D + lane];
        float v1 = H[(size_t)s * D + 64 + lane];
        atomicAdd(&AGG[(size_t)t * D + lane],      coef * v0);
        atomicAdd(&AGG[(size_t)t * D + 64 + lane], coef * v1);
    }
}

// ---------------- LayerNorm + ReLU (one wave per row) ----------------
__global__ __launch_bounds__(256) void k_ln_relu(const float* __restrict__ AGG,
                                                 const float* __restrict__ g,
                                                 const float* __restrict__ be,
                                                 float* __restrict__ OUT) {
    int wv   = threadIdx.x >> 6;
    int lane = threadIdx.x & 63;
    int row  = blockIdx.x * 4 + wv;
    if (row >= N_NODES) return;

    float a0 = AGG[(size_t)row * D + lane];
    float a1 = AGG[(size_t)row * D + 64 + lane];

    float s = a0 + a1;
    #pragma unroll
    for (int off = 32; off >= 1; off >>= 1) s += __shfl_xor(s, off);
    float mean = s * (1.0f / 128.0f);

    float d0 = a0 - mean, d1 = a1 - mean;
    float vs = d0 * d0 + d1 * d1;
    #pragma unroll
    for (int off = 32; off >= 1; off >>= 1) vs += __shfl_xor(vs, off);
    float inv = rsqrtf(vs * (1.0f / 128.0f) + 1e-5f);

    float y0 = d0 * inv * g[lane]      + be[lane];
    float y1 = d1 * inv * g[lane + 64] + be[lane + 64];
    OUT[(size_t)row * D + lane]      = fmaxf(y0, 0.0f);
    OUT[(size_t)row * D + 64 + lane] = fmaxf(y1, 0.0f);
}

// ---------------- final: out = concat(x,h1,h2) @ Wp + bp ----------------
__global__ __launch_bounds__(256) void k_final(const float* __restrict__ X,
                                               const float* __restrict__ H1,
                                               const float* __restrict__ H2,
                                               const float* __restrict__ Wp,
                                               const float* __restrict__ bp,
                                               float* __restrict__ OUT) {
    __shared__ float Wps[D_CAT * D_OUT];   // 96 KB
    __shared__ float rows[4][D_CAT];       // 6 KB
    for (int i = threadIdx.x; i < D_CAT * D_OUT; i += 256) Wps[i] = Wp[i];
    __syncthreads();

    int wv   = threadIdx.x >> 6;
    int lane = threadIdx.x & 63;

    for (int r = blockIdx.x * 4 + wv; r < N_NODES; r += gridDim.x * 4) {
        rows[wv][lane]       = X [(size_t)r * D + lane];
        rows[wv][64 + lane]  = X [(size_t)r * D + 64 + lane];
        rows[wv][128 + lane] = H1[(size_t)r * D + lane];
        rows[wv][192 + lane] = H1[(size_t)r * D + 64 + lane];
        rows[wv][256 + lane] = H2[(size_t)r * D + lane];
        rows[wv][320 + lane] = H2[(size_t)r * D + 64 + lane];
        // wave-private LDS; compiler inserts lgkmcnt waits before reads

        float acc = bp[lane];
        #pragma unroll 4
        for (int k = 0; k < D_CAT; ++k)
            acc = fmaf(rows[wv][k], Wps[k * D_OUT + lane], acc);
        OUT[(size_t)r * D_OUT + lane] = acc;
    }
}

// ---------------- launcher ----------------
extern "C" void kernel_launch(void* const* d_in, const int* in_sizes, int n_in,
                              void* d_out, int out_size, void* d_ws, size_t ws_size,
                              hipStream_t stream) {
    const float* x   = (const float*)d_in[0];
    const int*   ei  = (const int*)  d_in[1];   // [2, E] int32
    const float* W1  = (const float*)d_in[2];
    const float* b1  = (const float*)d_in[3];
    const float* g1  = (const float*)d_in[4];
    const float* be1 = (const float*)d_in[5];
    const float* W2  = (const float*)d_in[6];
    const float* b2  = (const float*)d_in[7];
    const float* g2  = (const float*)d_in[8];
    const float* be2 = (const float*)d_in[9];
    const float* Wp  = (const float*)d_in[10];
    const float* bp  = (const float*)d_in[11];
    float* out = (float*)d_out;

    const int* tgt = ei;            // edge_index[0] (targets / row)
    const int* src = ei + N_EDGES;  // edge_index[1] (sources / col)

    float* ws = (float*)d_ws;
    float* dis = ws;                          // 40000   (padded to 40960)
    float* tmp = ws + 40960;                  // 5,120,000
    float* agg = tmp + (size_t)N_NODES * D;   // 5,120,000
    float* h1  = agg + (size_t)N_NODES * D;   // 5,120,000
    float* h2  = h1  + (size_t)N_NODES * D;   // 5,120,000

    const int B = 256;

    // degree + dis
    k_deg_init <<<(N_NODES + B - 1) / B, B, 0, stream>>>(dis);
    k_deg_edges<<<(N_EDGES + B - 1) / B, B, 0, stream>>>(tgt, dis);
    k_dis      <<<(N_NODES + B - 1) / B, B, 0, stream>>>(dis);

    // ---- block 1 ----
    k_gemm128  <<<2048, B, 0, stream>>>(x, W1, tmp);
    k_agg_init <<<(N_NODES * D / 4 + B - 1) / B, B, 0, stream>>>(tmp, dis, b1, agg);
    k_agg_edges<<<8192, B, 0, stream>>>(tgt, src, dis, tmp, agg);
    k_ln_relu  <<<(N_NODES + 3) / 4, B, 0, stream>>>(agg, g1, be1, h1);

    // ---- block 2 ----
    k_gemm128  <<<2048, B, 0, stream>>>(h1, W2, tmp);
    k_agg_init <<<(N_NODES * D / 4 + B - 1) / B, B, 0, stream>>>(tmp, dis, b2, agg);
    k_agg_edges<<<8192, B, 0, stream>>>(tgt, src, dis, tmp, agg);
    k_ln_relu  <<<(N_NODES + 3) / 4, B, 0, stream>>>(agg, g2, be2, h2);

    // ---- jumping-knowledge concat + projection ----
    k_final    <<<2048, B, 0, stream>>>(x, h1, h2, Wp, bp, out);
}

// Round 2
// 613.899 us; speedup vs baseline: 1.5917x; 1.5917x over previous
//
#include <hip/hip_runtime.h>
#include <math.h>

#define N_NODES 40000
#define N_EDGES 640000
#define D 128
#define D_OUT 64
#define D_CAT 384

// ---------------- CSR build ----------------
__global__ void k_zero(int* __restrict__ deg, int* __restrict__ cnt) {
    int i = blockIdx.x * blockDim.x + threadIdx.x;
    if (i < 40960) { deg[i] = 0; cnt[i] = 0; }
}

__global__ void k_deg_edges(const int* __restrict__ tgt, int* __restrict__ deg) {
    int e = blockIdx.x * blockDim.x + threadIdx.x;
    if (e < N_EDGES) atomicAdd(&deg[tgt[e]], 1);
}

__global__ void k_dis(const int* __restrict__ deg, float* __restrict__ dis) {
    int i = blockIdx.x * blockDim.x + threadIdx.x;
    if (i < N_NODES) dis[i] = rsqrtf((float)deg[i] + 1.0f);  // +1 self-loop
}

// single block, 256 threads: exclusive scan of deg -> row_ptr[0..N]
__global__ __launch_bounds__(256) void k_scan(const int* __restrict__ deg,
                                              int* __restrict__ row_ptr) {
    __shared__ int sums[256];
    const int SEG = 157;  // 157*256 = 40192 >= 40000
    int t = threadIdx.x;
    int beg = t * SEG;
    int end = beg + SEG; if (end > N_NODES) end = N_NODES;
    int s = 0;
    for (int i = beg; i < end; ++i) s += deg[i];
    sums[t] = s;
    __syncthreads();
    for (int off = 1; off < 256; off <<= 1) {
        int v = (t >= off) ? sums[t - off] : 0;
        __syncthreads();
        sums[t] += v;
        __syncthreads();
    }
    int base = (t == 0) ? 0 : sums[t - 1];
    for (int i = beg; i < end; ++i) { row_ptr[i] = base; base += deg[i]; }
    if (t == 255) row_ptr[N_NODES] = base;
}

__global__ void k_scatter(const int* __restrict__ tgt, const int* __restrict__ src,
                          const int* __restrict__ row_ptr, int* __restrict__ cnt,
                          const float* __restrict__ dis,
                          int* __restrict__ col, float* __restrict__ coef) {
    int e = blockIdx.x * blockDim.x + threadIdx.x;
    if (e >= N_EDGES) return;
    int t = tgt[e];
    int s = src[e];
    int pos = row_ptr[t] + atomicAdd(&cnt[t], 1);
    col[pos]  = s;
    coef[pos] = dis[t] * dis[s];
}

// ---------------- GEMM: H = X @ W   (X: [N,128], W: [128,128]) ----------------
__global__ __launch_bounds__(256) void k_gemm128(const float* __restrict__ X,
                                                 const float* __restrict__ W,
                                                 float* __restrict__ H) {
    __shared__ float Ws[128 * 128];   // 64 KB
    __shared__ float Xs[2][128];
    for (int i = threadIdx.x; i < 128 * 128; i += 256) Ws[i] = W[i];
    __syncthreads();

    int rs = threadIdx.x >> 7;   // 0..1 : which of the 2 rows
    int cj = threadIdx.x & 127;  // output column

    for (int row0 = blockIdx.x * 2; row0 < N_NODES; row0 += gridDim.x * 2) {
        int r = row0 + rs;
        if (r < N_NODES) Xs[rs][cj] = X[(size_t)r * D + cj];
        __syncthreads();
        if (r < N_NODES) {
            float acc = 0.0f;
            #pragma unroll 8
            for (int k = 0; k < 128; ++k)
                acc = fmaf(Xs[rs][k], Ws[k * 128 + cj], acc);
            H[(size_t)r * D + cj] = acc;
        }
        __syncthreads();
    }
}

// ---------------- fused CSR aggregate + bias + self-loop + LayerNorm + ReLU ----
// one wave per node; lane holds dims {2*lane, 2*lane+1} as float2
__global__ __launch_bounds__(256) void k_agg_ln(const float* __restrict__ H,
                                                const float* __restrict__ dis,
                                                const int* __restrict__ row_ptr,
                                                const int* __restrict__ col,
                                                const float* __restrict__ coef,
                                                const float* __restrict__ b,
                                                const float* __restrict__ g,
                                                const float* __restrict__ be,
                                                float* __restrict__ OUT) {
    int wv   = threadIdx.x >> 6;
    int lane = threadIdx.x & 63;
    int i    = blockIdx.x * 4 + wv;
    if (i >= N_NODES) return;

    const float2* H2 = (const float2*)H;
    float  di = dis[i];
    float2 hh = H2[(size_t)i * 64 + lane];
    float2 bb = ((const float2*)b)[lane];
    float a0 = bb.x + di * di * hh.x;
    float a1 = bb.y + di * di * hh.y;

    int e   = row_ptr[i];
    int end = row_ptr[i + 1];
    for (; e + 1 < end; e += 2) {
        int   s0 = col[e],     s1 = col[e + 1];
        float c0 = coef[e],    c1 = coef[e + 1];
        float2 v0 = H2[(size_t)s0 * 64 + lane];
        float2 v1 = H2[(size_t)s1 * 64 + lane];
        a0 += c0 * v0.x; a1 += c0 * v0.y;
        a0 += c1 * v1.x; a1 += c1 * v1.y;
    }
    if (e < end) {
        int   s0 = col[e];
        float c0 = coef[e];
        float2 v0 = H2[(size_t)s0 * 64 + lane];
        a0 += c0 * v0.x; a1 += c0 * v0.y;
    }

    // LayerNorm over 128 dims (wave reduce) + ReLU
    float s = a0 + a1;
    #pragma unroll
    for (int off = 32; off >= 1; off >>= 1) s += __shfl_xor(s, off);
    float mean = s * (1.0f / 128.0f);

    float d0 = a0 - mean, d1 = a1 - mean;
    float vs = d0 * d0 + d1 * d1;
    #pragma unroll
    for (int off = 32; off >= 1; off >>= 1) vs += __shfl_xor(vs, off);
    float inv = rsqrtf(vs * (1.0f / 128.0f) + 1e-5f);

    float2 gg = ((const float2*)g)[lane];
    float2 ee = ((const float2*)be)[lane];
    float2 o;
    o.x = fmaxf(d0 * inv * gg.x + ee.x, 0.0f);
    o.y = fmaxf(d1 * inv * gg.y + ee.y, 0.0f);
    ((float2*)OUT)[(size_t)i * 64 + lane] = o;
}

// ---------------- final: out = concat(x,h1,h2) @ Wp + bp ----------------
__global__ __launch_bounds__(256) void k_final(const float* __restrict__ X,
                                               const float* __restrict__ H1,
                                               const float* __restrict__ H2,
                                               const float* __restrict__ Wp,
                                               const float* __restrict__ bp,
                                               float* __restrict__ OUT) {
    __shared__ float Wps[D_CAT * D_OUT];   // 96 KB
    __shared__ float rows[4][D_CAT];       // 6 KB
    for (int i = threadIdx.x; i < D_CAT * D_OUT; i += 256) Wps[i] = Wp[i];
    __syncthreads();

    int wv   = threadIdx.x >> 6;
    int lane = threadIdx.x & 63;

    for (int r = blockIdx.x * 4 + wv; r < N_NODES; r += gridDim.x * 4) {
        rows[wv][lane]       = X [(size_t)r * D + lane];
        rows[wv][64 + lane]  = X [(size_t)r * D + 64 + lane];
        rows[wv][128 + lane] = H1[(size_t)r * D + lane];
        rows[wv][192 + lane] = H1[(size_t)r * D + 64 + lane];
        rows[wv][256 + lane] = H2[(size_t)r * D + lane];
        rows[wv][320 + lane] = H2[(size_t)r * D + 64 + lane];

        float acc = bp[lane];
        #pragma unroll 4
        for (int k = 0; k < D_CAT; ++k)
            acc = fmaf(rows[wv][k], Wps[k * D_OUT + lane], acc);
        OUT[(size_t)r * D_OUT + lane] = acc;
    }
}

// ---------------- launcher ----------------
extern "C" void kernel_launch(void* const* d_in, const int* in_sizes, int n_in,
                              void* d_out, int out_size, void* d_ws, size_t ws_size,
                              hipStream_t stream) {
    const float* x   = (const float*)d_in[0];
    const int*   ei  = (const int*)  d_in[1];   // [2, E] int32
    const float* W1  = (const float*)d_in[2];
    const float* b1  = (const float*)d_in[3];
    const float* g1  = (const float*)d_in[4];
    const float* be1 = (const float*)d_in[5];
    const float* W2  = (const float*)d_in[6];
    const float* b2  = (const float*)d_in[7];
    const float* g2  = (const float*)d_in[8];
    const float* be2 = (const float*)d_in[9];
    const float* Wp  = (const float*)d_in[10];
    const float* bp  = (const float*)d_in[11];
    float* out = (float*)d_out;

    const int* tgt = ei;            // edge_index[0] (targets / row)
    const int* src = ei + N_EDGES;  // edge_index[1] (sources / col)

    char* ws = (char*)d_ws;
    int*   deg_i   = (int*)   ws;               ws += 40960 * 4;
    int*   cnt     = (int*)   ws;               ws += 40960 * 4;
    int*   row_ptr = (int*)   ws;               ws += 41984 * 4;
    int*   col     = (int*)   ws;               ws += (size_t)N_EDGES * 4;
    float* coef    = (float*) ws;               ws += (size_t)N_EDGES * 4;
    float* dis     = (float*) ws;               ws += 40960 * 4;
    float* tmp     = (float*) ws;               ws += (size_t)N_NODES * D * 4;
    float* h1      = (float*) ws;               ws += (size_t)N_NODES * D * 4;
    float* h2      = (float*) ws;               ws += (size_t)N_NODES * D * 4;

    const int B = 256;

    // CSR build
    k_zero     <<<(40960 + B - 1) / B, B, 0, stream>>>(deg_i, cnt);
    k_deg_edges<<<(N_EDGES + B - 1) / B, B, 0, stream>>>(tgt, deg_i);
    k_dis      <<<(N_NODES + B - 1) / B, B, 0, stream>>>(deg_i, dis);
    k_scan     <<<1, B, 0, stream>>>(deg_i, row_ptr);
    k_scatter  <<<(N_EDGES + B - 1) / B, B, 0, stream>>>(tgt, src, row_ptr, cnt, dis, col, coef);

    // ---- block 1 ----
    k_gemm128  <<<2048, B, 0, stream>>>(x, W1, tmp);
    k_agg_ln   <<<(N_NODES + 3) / 4, B, 0, stream>>>(tmp, dis, row_ptr, col, coef, b1, g1, be1, h1);

    // ---- block 2 ----
    k_gemm128  <<<2048, B, 0, stream>>>(h1, W2, tmp);
    k_agg_ln   <<<(N_NODES + 3) / 4, B, 0, stream>>>(tmp, dis, row_ptr, col, coef, b2, g2, be2, h2);

    // ---- jumping-knowledge concat + projection ----
    k_final    <<<2048, B, 0, stream>>>(x, h1, h2, Wp, bp, out);
}

// Round 3
// 326.279 us; speedup vs baseline: 2.9949x; 1.8815x over previous
//
#include <hip/hip_runtime.h>
#include <math.h>

#define N_NODES 40000
#define N_EDGES 640000
#define D 128
#define D_OUT 64

// ---------------- CSR build ----------------
__global__ void k_zero(int* __restrict__ deg, int* __restrict__ cnt) {
    int i = blockIdx.x * blockDim.x + threadIdx.x;
    if (i < 40960) { deg[i] = 0; cnt[i] = 0; }
}

__global__ void k_deg_edges(const int* __restrict__ tgt, int* __restrict__ deg) {
    int e = blockIdx.x * blockDim.x + threadIdx.x;
    if (e < N_EDGES) atomicAdd(&deg[tgt[e]], 1);
}

__global__ void k_dis(const int* __restrict__ deg, float* __restrict__ dis) {
    int i = blockIdx.x * blockDim.x + threadIdx.x;
    if (i < N_NODES) dis[i] = rsqrtf((float)deg[i] + 1.0f);  // +1 self-loop
}

// single block, 256 threads: exclusive scan of deg -> row_ptr[0..N]
__global__ __launch_bounds__(256) void k_scan(const int* __restrict__ deg,
                                              int* __restrict__ row_ptr) {
    __shared__ int sums[256];
    const int SEG = 157;  // 157*256 = 40192 >= 40000
    int t = threadIdx.x;
    int beg = t * SEG;
    int end = beg + SEG; if (end > N_NODES) end = N_NODES;
    int s = 0;
    for (int i = beg; i < end; ++i) s += deg[i];
    sums[t] = s;
    __syncthreads();
    for (int off = 1; off < 256; off <<= 1) {
        int v = (t >= off) ? sums[t - off] : 0;
        __syncthreads();
        sums[t] += v;
        __syncthreads();
    }
    int base = (t == 0) ? 0 : sums[t - 1];
    for (int i = beg; i < end; ++i) { row_ptr[i] = base; base += deg[i]; }
    if (t == 255) row_ptr[N_NODES] = base;
}

__global__ void k_scatter(const int* __restrict__ tgt, const int* __restrict__ src,
                          const int* __restrict__ row_ptr, int* __restrict__ cnt,
                          const float* __restrict__ dis,
                          int* __restrict__ col, float* __restrict__ coef) {
    int e = blockIdx.x * blockDim.x + threadIdx.x;
    if (e >= N_EDGES) return;
    int t = tgt[e];
    int s = src[e];
    int pos = row_ptr[t] + atomicAdd(&cnt[t], 1);
    col[pos]  = s;
    coef[pos] = dis[t] * dis[s];
}

// ---------------- register-tiled f32 GEMM ----------------
// C[M x Ntot] = concat_k(A0,A1,A2)[M x KTOT] @ W[KTOT x Ntot] (+ bias)
// tile: BM x 64, BK=32. 256 threads, per-thread TM rows x 4 cols.
// A staged transposed in LDS (pad +4 keeps 16B alignment for b128 reads).
template<int BM, int TM, int KTOT, int NSRC, bool BIAS>
__global__ __launch_bounds__(256) void k_gemm_tiled(const float* __restrict__ A0,
                                                    const float* __restrict__ A1,
                                                    const float* __restrict__ A2,
                                                    const float* __restrict__ W,
                                                    const float* __restrict__ bias,
                                                    float* __restrict__ C,
                                                    int Ntot) {
    __shared__ float AT[32][BM + 4];
    __shared__ float Bs[32][64];

    const int t  = threadIdx.x;
    const int tx = t & 15;        // col group: 4 cols each
    const int ty = t >> 4;        // row group: TM rows each
    const int m0 = blockIdx.x * BM;
    const int n0 = blockIdx.y * 64;

    float acc[TM][4];
    #pragma unroll
    for (int i = 0; i < TM; ++i)
        #pragma unroll
        for (int j = 0; j < 4; ++j) acc[i][j] = 0.0f;

    for (int kt = 0; kt < KTOT / 32; ++kt) {
        // pick A source (concat along K; each source is 128 wide)
        const float* Ap;
        int kbase;
        if (NSRC == 1) { Ap = A0; kbase = kt * 32; }
        else {
            int s = (kt * 32) >> 7;
            Ap = (s == 0) ? A0 : ((s == 1) ? A1 : A2);
            kbase = (kt * 32) & 127;
        }

        // stage A transposed: thread reads A[r][k0..k0+3], writes AT[k0+j][r]
        {
            int k0 = (t & 7) * 4;
            for (int rr = t >> 3; rr < BM; rr += 32) {
                int rg = m0 + rr; if (rg > N_NODES - 1) rg = N_NODES - 1;
                const float4 v = *(const float4*)&Ap[(size_t)rg * D + kbase + k0];
                AT[k0 + 0][rr] = v.x;
                AT[k0 + 1][rr] = v.y;
                AT[k0 + 2][rr] = v.z;
                AT[k0 + 3][rr] = v.w;
            }
        }
        // stage B: Bs[k][c] = W[kt*32+k][n0+c]
        {
            int c0 = tx * 4;
            for (int kk = ty; kk < 32; kk += 16)
                *(float4*)&Bs[kk][c0] =
                    *(const float4*)&W[(size_t)(kt * 32 + kk) * Ntot + n0 + c0];
        }
        __syncthreads();

        #pragma unroll
        for (int k = 0; k < 32; ++k) {
            float4 b = *(const float4*)&Bs[k][tx * 4];
            float a[TM];
            {
                const float4 a0 = *(const float4*)&AT[k][ty * TM];
                a[0] = a0.x; a[1] = a0.y; a[2] = a0.z; a[3] = a0.w;
                if (TM == 8) {
                    const float4 a1 = *(const float4*)&AT[k][ty * TM + 4];
                    a[4] = a1.x; a[5] = a1.y; a[6] = a1.z; a[7] = a1.w;
                }
            }
            #pragma unroll
            for (int i = 0; i < TM; ++i) {
                acc[i][0] = fmaf(a[i], b.x, acc[i][0]);
                acc[i][1] = fmaf(a[i], b.y, acc[i][1]);
                acc[i][2] = fmaf(a[i], b.z, acc[i][2]);
                acc[i][3] = fmaf(a[i], b.w, acc[i][3]);
            }
        }
        __syncthreads();
    }

    float4 bb = make_float4(0.f, 0.f, 0.f, 0.f);
    if (BIAS) bb = *(const float4*)&bias[n0 + tx * 4];
    #pragma unroll
    for (int i = 0; i < TM; ++i) {
        int r = m0 + ty * TM + i;
        if (r < N_NODES) {
            float4 o;
            o.x = acc[i][0] + bb.x;
            o.y = acc[i][1] + bb.y;
            o.z = acc[i][2] + bb.z;
            o.w = acc[i][3] + bb.w;
            *(float4*)&C[(size_t)r * Ntot + n0 + tx * 4] = o;
        }
    }
}

// ---------------- fused CSR aggregate + bias + self-loop + LayerNorm + ReLU ----
__global__ __launch_bounds__(256) void k_agg_ln(const float* __restrict__ H,
                                                const float* __restrict__ dis,
                                                const int* __restrict__ row_ptr,
                                                const int* __restrict__ col,
                                                const float* __restrict__ coef,
                                                const float* __restrict__ b,
                                                const float* __restrict__ g,
                                                const float* __restrict__ be,
                                                float* __restrict__ OUT) {
    int wv   = threadIdx.x >> 6;
    int lane = threadIdx.x & 63;
    int i    = blockIdx.x * 4 + wv;
    if (i >= N_NODES) return;

    const float2* H2 = (const float2*)H;
    float  di = dis[i];
    float2 hh = H2[(size_t)i * 64 + lane];
    float2 bb = ((const float2*)b)[lane];
    float a0 = bb.x + di * di * hh.x;
    float a1 = bb.y + di * di * hh.y;

    int e   = row_ptr[i];
    int end = row_ptr[i + 1];
    for (; e + 1 < end; e += 2) {
        int   s0 = col[e],     s1 = col[e + 1];
        float c0 = coef[e],    c1 = coef[e + 1];
        float2 v0 = H2[(size_t)s0 * 64 + lane];
        float2 v1 = H2[(size_t)s1 * 64 + lane];
        a0 += c0 * v0.x; a1 += c0 * v0.y;
        a0 += c1 * v1.x; a1 += c1 * v1.y;
    }
    if (e < end) {
        int   s0 = col[e];
        float c0 = coef[e];
        float2 v0 = H2[(size_t)s0 * 64 + lane];
        a0 += c0 * v0.x; a1 += c0 * v0.y;
    }

    float s = a0 + a1;
    #pragma unroll
    for (int off = 32; off >= 1; off >>= 1) s += __shfl_xor(s, off);
    float mean = s * (1.0f / 128.0f);

    float d0 = a0 - mean, d1 = a1 - mean;
    float vs = d0 * d0 + d1 * d1;
    #pragma unroll
    for (int off = 32; off >= 1; off >>= 1) vs += __shfl_xor(vs, off);
    float inv = rsqrtf(vs * (1.0f / 128.0f) + 1e-5f);

    float2 gg = ((const float2*)g)[lane];
    float2 ee = ((const float2*)be)[lane];
    float2 o;
    o.x = fmaxf(d0 * inv * gg.x + ee.x, 0.0f);
    o.y = fmaxf(d1 * inv * gg.y + ee.y, 0.0f);
    ((float2*)OUT)[(size_t)i * 64 + lane] = o;
}

// ---------------- launcher ----------------
extern "C" void kernel_launch(void* const* d_in, const int* in_sizes, int n_in,
                              void* d_out, int out_size, void* d_ws, size_t ws_size,
                              hipStream_t stream) {
    const float* x   = (const float*)d_in[0];
    const int*   ei  = (const int*)  d_in[1];   // [2, E] int32
    const float* W1  = (const float*)d_in[2];
    const float* b1  = (const float*)d_in[3];
    const float* g1  = (const float*)d_in[4];
    const float* be1 = (const float*)d_in[5];
    const float* W2  = (const float*)d_in[6];
    const float* b2  = (const float*)d_in[7];
    const float* g2  = (const float*)d_in[8];
    const float* be2 = (const float*)d_in[9];
    const float* Wp  = (const float*)d_in[10];
    const float* bp  = (const float*)d_in[11];
    float* out = (float*)d_out;

    const int* tgt = ei;            // edge_index[0] (targets / row)
    const int* src = ei + N_EDGES;  // edge_index[1] (sources / col)

    char* ws = (char*)d_ws;
    int*   deg_i   = (int*)   ws;               ws += 40960 * 4;
    int*   cnt     = (int*)   ws;               ws += 40960 * 4;
    int*   row_ptr = (int*)   ws;               ws += 41984 * 4;
    int*   col     = (int*)   ws;               ws += (size_t)N_EDGES * 4;
    float* coef    = (float*) ws;               ws += (size_t)N_EDGES * 4;
    float* dis     = (float*) ws;               ws += 40960 * 4;
    float* tmp     = (float*) ws;               ws += (size_t)N_NODES * D * 4;
    float* h1      = (float*) ws;               ws += (size_t)N_NODES * D * 4;
    float* h2      = (float*) ws;               ws += (size_t)N_NODES * D * 4;

    const int B = 256;

    // CSR build
    k_zero     <<<(40960 + B - 1) / B, B, 0, stream>>>(deg_i, cnt);
    k_deg_edges<<<(N_EDGES + B - 1) / B, B, 0, stream>>>(tgt, deg_i);
    k_dis      <<<(N_NODES + B - 1) / B, B, 0, stream>>>(deg_i, dis);
    k_scan     <<<1, B, 0, stream>>>(deg_i, row_ptr);
    k_scatter  <<<(N_EDGES + B - 1) / B, B, 0, stream>>>(tgt, src, row_ptr, cnt, dis, col, coef);

    // ---- block 1: H = X @ W1 ----
    k_gemm_tiled<128, 8, 128, 1, false><<<dim3(313, 2), B, 0, stream>>>(
        x, nullptr, nullptr, W1, nullptr, tmp, 128);
    k_agg_ln   <<<(N_NODES + 3) / 4, B, 0, stream>>>(tmp, dis, row_ptr, col, coef, b1, g1, be1, h1);

    // ---- block 2: H = h1 @ W2 ----
    k_gemm_tiled<128, 8, 128, 1, false><<<dim3(313, 2), B, 0, stream>>>(
        h1, nullptr, nullptr, W2, nullptr, tmp, 128);
    k_agg_ln   <<<(N_NODES + 3) / 4, B, 0, stream>>>(tmp, dis, row_ptr, col, coef, b2, g2, be2, h2);

    // ---- jumping-knowledge concat + projection: out = [x,h1,h2] @ Wp + bp ----
    k_gemm_tiled<64, 4, 384, 3, true><<<dim3(625, 1), B, 0, stream>>>(
        x, h1, h2, Wp, bp, out, 64);
}

// Round 4
// 265.481 us; speedup vs baseline: 3.6807x; 1.2290x over previous
//
#include <hip/hip_runtime.h>
#include <math.h>

#define N_NODES 40000
#define N_EDGES 640000
#define D 128
#define D_OUT 64
#define SCAN_NBLK 157   // ceil(40000/256)

// ---------------- CSR build ----------------
__global__ void k_zero(int* __restrict__ deg, int* __restrict__ cnt) {
    int i = blockIdx.x * blockDim.x + threadIdx.x;
    if (i < 40960) { deg[i] = 0; cnt[i] = 0; }
}

__global__ void k_deg_edges(const int* __restrict__ tgt, int* __restrict__ deg) {
    int e = blockIdx.x * blockDim.x + threadIdx.x;
    if (e < N_EDGES) atomicAdd(&deg[tgt[e]], 1);
}

// level-1 scan: per-block exclusive scan of deg -> row_ptr (local), block sums
// -> partials. Also fuses dis = rsqrt(deg+1).
__global__ __launch_bounds__(256) void k_scan1(const int* __restrict__ deg,
                                               int* __restrict__ row_ptr,
                                               int* __restrict__ partials,
                                               float* __restrict__ dis) {
    __shared__ int s[256];
    int t = threadIdx.x;
    int i = blockIdx.x * 256 + t;
    int v = (i < N_NODES) ? deg[i] : 0;
    if (i < N_NODES) dis[i] = rsqrtf((float)v + 1.0f);  // +1 self-loop
    s[t] = v;
    __syncthreads();
    #pragma unroll
    for (int off = 1; off < 256; off <<= 1) {
        int u = (t >= off) ? s[t - off] : 0;
        __syncthreads();
        s[t] += u;
        __syncthreads();
    }
    if (i < N_NODES) row_ptr[i] = s[t] - v;      // local exclusive
    if (t == 255) partials[blockIdx.x] = s[255]; // block total
}

// level-2: single block scans the 157 partials (exclusive, in place)
__global__ __launch_bounds__(256) void k_scan2(int* __restrict__ partials) {
    __shared__ int s[256];
    int t = threadIdx.x;
    int v = (t < SCAN_NBLK) ? partials[t] : 0;
    s[t] = v;
    __syncthreads();
    #pragma unroll
    for (int off = 1; off < 256; off <<= 1) {
        int u = (t >= off) ? s[t - off] : 0;
        __syncthreads();
        s[t] += u;
        __syncthreads();
    }
    if (t < SCAN_NBLK) partials[t] = s[t] - v;   // exclusive
}

// level-3: add block offsets; row_ptr[N] = E (constant by construction)
__global__ void k_scan3(int* __restrict__ row_ptr, const int* __restrict__ partials) {
    int i = blockIdx.x * blockDim.x + threadIdx.x;
    if (i < N_NODES) row_ptr[i] += partials[blockIdx.x];
    if (i == N_NODES) row_ptr[N_NODES] = N_EDGES;
}

__global__ void k_scatter(const int* __restrict__ tgt, const int* __restrict__ src,
                          const int* __restrict__ row_ptr, int* __restrict__ cnt,
                          const float* __restrict__ dis,
                          int* __restrict__ col, float* __restrict__ coef) {
    int e = blockIdx.x * blockDim.x + threadIdx.x;
    if (e >= N_EDGES) return;
    int t = tgt[e];
    int s = src[e];
    int pos = row_ptr[t] + atomicAdd(&cnt[t], 1);
    col[pos]  = s;
    coef[pos] = dis[t] * dis[s];
}

// ---------------- register-tiled f32 GEMM ----------------
// C[M x Ntot] = concat_k(A0,A1,A2)[M x KTOT] @ W[KTOT x Ntot] (+ bias)
template<int BM, int TM, int KTOT, int NSRC, bool BIAS>
__global__ __launch_bounds__(256) void k_gemm_tiled(const float* __restrict__ A0,
                                                    const float* __restrict__ A1,
                                                    const float* __restrict__ A2,
                                                    const float* __restrict__ W,
                                                    const float* __restrict__ bias,
                                                    float* __restrict__ C,
                                                    int Ntot) {
    __shared__ float AT[32][BM + 4];
    __shared__ float Bs[32][64];

    const int t  = threadIdx.x;
    const int tx = t & 15;        // col group: 4 cols each
    const int ty = t >> 4;        // row group: TM rows each
    const int m0 = blockIdx.x * BM;
    const int n0 = blockIdx.y * 64;

    float acc[TM][4];
    #pragma unroll
    for (int i = 0; i < TM; ++i)
        #pragma unroll
        for (int j = 0; j < 4; ++j) acc[i][j] = 0.0f;

    for (int kt = 0; kt < KTOT / 32; ++kt) {
        const float* Ap;
        int kbase;
        if (NSRC == 1) { Ap = A0; kbase = kt * 32; }
        else {
            int s = (kt * 32) >> 7;
            Ap = (s == 0) ? A0 : ((s == 1) ? A1 : A2);
            kbase = (kt * 32) & 127;
        }

        {
            int k0 = (t & 7) * 4;
            for (int rr = t >> 3; rr < BM; rr += 32) {
                int rg = m0 + rr; if (rg > N_NODES - 1) rg = N_NODES - 1;
                const float4 v = *(const float4*)&Ap[(size_t)rg * D + kbase + k0];
                AT[k0 + 0][rr] = v.x;
                AT[k0 + 1][rr] = v.y;
                AT[k0 + 2][rr] = v.z;
                AT[k0 + 3][rr] = v.w;
            }
        }
        {
            int c0 = tx * 4;
            for (int kk = ty; kk < 32; kk += 16)
                *(float4*)&Bs[kk][c0] =
                    *(const float4*)&W[(size_t)(kt * 32 + kk) * Ntot + n0 + c0];
        }
        __syncthreads();

        #pragma unroll
        for (int k = 0; k < 32; ++k) {
            float4 b = *(const float4*)&Bs[k][tx * 4];
            float a[TM];
            {
                const float4 a0 = *(const float4*)&AT[k][ty * TM];
                a[0] = a0.x; a[1] = a0.y; a[2] = a0.z; a[3] = a0.w;
                if (TM == 8) {
                    const float4 a1 = *(const float4*)&AT[k][ty * TM + 4];
                    a[4] = a1.x; a[5] = a1.y; a[6] = a1.z; a[7] = a1.w;
                }
            }
            #pragma unroll
            for (int i = 0; i < TM; ++i) {
                acc[i][0] = fmaf(a[i], b.x, acc[i][0]);
                acc[i][1] = fmaf(a[i], b.y, acc[i][1]);
                acc[i][2] = fmaf(a[i], b.z, acc[i][2]);
                acc[i][3] = fmaf(a[i], b.w, acc[i][3]);
            }
        }
        __syncthreads();
    }

    float4 bb = make_float4(0.f, 0.f, 0.f, 0.f);
    if (BIAS) bb = *(const float4*)&bias[n0 + tx * 4];
    #pragma unroll
    for (int i = 0; i < TM; ++i) {
        int r = m0 + ty * TM + i;
        if (r < N_NODES) {
            float4 o;
            o.x = acc[i][0] + bb.x;
            o.y = acc[i][1] + bb.y;
            o.z = acc[i][2] + bb.z;
            o.w = acc[i][3] + bb.w;
            *(float4*)&C[(size_t)r * Ntot + n0 + tx * 4] = o;
        }
    }
}

// ---------------- fused CSR aggregate + bias + self-loop + LayerNorm + ReLU ----
__global__ __launch_bounds__(256) void k_agg_ln(const float* __restrict__ H,
                                                const float* __restrict__ dis,
                                                const int* __restrict__ row_ptr,
                                                const int* __restrict__ col,
                                                const float* __restrict__ coef,
                                                const float* __restrict__ b,
                                                const float* __restrict__ g,
                                                const float* __restrict__ be,
                                                float* __restrict__ OUT) {
    int wv   = threadIdx.x >> 6;
    int lane = threadIdx.x & 63;
    int i    = blockIdx.x * 4 + wv;
    if (i >= N_NODES) return;

    const float2* H2 = (const float2*)H;
    float  di = dis[i];
    float2 hh = H2[(size_t)i * 64 + lane];
    float2 bb = ((const float2*)b)[lane];
    float a0 = bb.x + di * di * hh.x;
    float a1 = bb.y + di * di * hh.y;

    int e   = row_ptr[i];
    int end = row_ptr[i + 1];
    for (; e + 1 < end; e += 2) {
        int   s0 = col[e],     s1 = col[e + 1];
        float c0 = coef[e],    c1 = coef[e + 1];
        float2 v0 = H2[(size_t)s0 * 64 + lane];
        float2 v1 = H2[(size_t)s1 * 64 + lane];
        a0 += c0 * v0.x; a1 += c0 * v0.y;
        a0 += c1 * v1.x; a1 += c1 * v1.y;
    }
    if (e < end) {
        int   s0 = col[e];
        float c0 = coef[e];
        float2 v0 = H2[(size_t)s0 * 64 + lane];
        a0 += c0 * v0.x; a1 += c0 * v0.y;
    }

    float s = a0 + a1;
    #pragma unroll
    for (int off = 32; off >= 1; off >>= 1) s += __shfl_xor(s, off);
    float mean = s * (1.0f / 128.0f);

    float d0 = a0 - mean, d1 = a1 - mean;
    float vs = d0 * d0 + d1 * d1;
    #pragma unroll
    for (int off = 32; off >= 1; off >>= 1) vs += __shfl_xor(vs, off);
    float inv = rsqrtf(vs * (1.0f / 128.0f) + 1e-5f);

    float2 gg = ((const float2*)g)[lane];
    float2 ee = ((const float2*)be)[lane];
    float2 o;
    o.x = fmaxf(d0 * inv * gg.x + ee.x, 0.0f);
    o.y = fmaxf(d1 * inv * gg.y + ee.y, 0.0f);
    ((float2*)OUT)[(size_t)i * 64 + lane] = o;
}

// ---------------- launcher ----------------
extern "C" void kernel_launch(void* const* d_in, const int* in_sizes, int n_in,
                              void* d_out, int out_size, void* d_ws, size_t ws_size,
                              hipStream_t stream) {
    const float* x   = (const float*)d_in[0];
    const int*   ei  = (const int*)  d_in[1];   // [2, E] int32
    const float* W1  = (const float*)d_in[2];
    const float* b1  = (const float*)d_in[3];
    const float* g1  = (const float*)d_in[4];
    const float* be1 = (const float*)d_in[5];
    const float* W2  = (const float*)d_in[6];
    const float* b2  = (const float*)d_in[7];
    const float* g2  = (const float*)d_in[8];
    const float* be2 = (const float*)d_in[9];
    const float* Wp  = (const float*)d_in[10];
    const float* bp  = (const float*)d_in[11];
    float* out = (float*)d_out;

    const int* tgt = ei;            // edge_index[0] (targets / row)
    const int* src = ei + N_EDGES;  // edge_index[1] (sources / col)

    char* ws = (char*)d_ws;
    int*   deg_i   = (int*)   ws;               ws += 40960 * 4;
    int*   cnt     = (int*)   ws;               ws += 40960 * 4;
    int*   row_ptr = (int*)   ws;               ws += 41984 * 4;
    int*   partials= (int*)   ws;               ws += 256 * 4;
    int*   col     = (int*)   ws;               ws += (size_t)N_EDGES * 4;
    float* coef    = (float*) ws;               ws += (size_t)N_EDGES * 4;
    float* dis     = (float*) ws;               ws += 40960 * 4;
    float* tmp     = (float*) ws;               ws += (size_t)N_NODES * D * 4;
    float* h1      = (float*) ws;               ws += (size_t)N_NODES * D * 4;
    float* h2      = (float*) ws;               ws += (size_t)N_NODES * D * 4;

    const int B = 256;

    // CSR build (hierarchical scan: 65us single-block scan -> ~10us)
    k_zero     <<<(40960 + B - 1) / B, B, 0, stream>>>(deg_i, cnt);
    k_deg_edges<<<(N_EDGES + B - 1) / B, B, 0, stream>>>(tgt, deg_i);
    k_scan1    <<<SCAN_NBLK, B, 0, stream>>>(deg_i, row_ptr, partials, dis);
    k_scan2    <<<1, B, 0, stream>>>(partials);
    k_scan3    <<<SCAN_NBLK + 1, B, 0, stream>>>(row_ptr, partials);
    k_scatter  <<<(N_EDGES + B - 1) / B, B, 0, stream>>>(tgt, src, row_ptr, cnt, dis, col, coef);

    // ---- block 1: H = X @ W1 ----
    k_gemm_tiled<128, 8, 128, 1, false><<<dim3(313, 2), B, 0, stream>>>(
        x, nullptr, nullptr, W1, nullptr, tmp, 128);
    k_agg_ln   <<<(N_NODES + 3) / 4, B, 0, stream>>>(tmp, dis, row_ptr, col, coef, b1, g1, be1, h1);

    // ---- block 2: H = h1 @ W2 ----
    k_gemm_tiled<128, 8, 128, 1, false><<<dim3(313, 2), B, 0, stream>>>(
        h1, nullptr, nullptr, W2, nullptr, tmp, 128);
    k_agg_ln   <<<(N_NODES + 3) / 4, B, 0, stream>>>(tmp, dis, row_ptr, col, coef, b2, g2, be2, h2);

    // ---- jumping-knowledge concat + projection: out = [x,h1,h2] @ Wp + bp ----
    k_gemm_tiled<64, 4, 384, 3, true><<<dim3(625, 1), B, 0, stream>>>(
        x, h1, h2, Wp, bp, out, 64);
}

// Round 5
// 225.878 us; speedup vs baseline: 4.3260x; 1.1753x over previous
//
#include <hip/hip_runtime.h>
#include <math.h>

#define N_NODES 40000
#define N_EDGES 640000
#define D 128
#define D_OUT 64
#define SCAN_NBLK 157   // ceil(40000/256)

__device__ __forceinline__ float bf2f(unsigned short u) {
    return __uint_as_float(((unsigned int)u) << 16);
}
__device__ __forceinline__ unsigned short f2bf(float f) {
    unsigned int u = __float_as_uint(f);
    return (unsigned short)((u + 0x7FFFu + ((u >> 16) & 1u)) >> 16);  // RNE
}

// ---------------- CSR build ----------------
__global__ void k_zero(int* __restrict__ deg, int* __restrict__ cnt) {
    int i = blockIdx.x * blockDim.x + threadIdx.x;
    if (i < 40960) { deg[i] = 0; cnt[i] = 0; }
}

__global__ void k_deg_edges(const int* __restrict__ tgt, int* __restrict__ deg) {
    int e = blockIdx.x * blockDim.x + threadIdx.x;
    if (e < N_EDGES) atomicAdd(&deg[tgt[e]], 1);
}

// level-1 scan: per-block exclusive scan of deg -> row_ptr (local), block sums
// -> partials. Also fuses dis = rsqrt(deg+1).
__global__ __launch_bounds__(256) void k_scan1(const int* __restrict__ deg,
                                               int* __restrict__ row_ptr,
                                               int* __restrict__ partials,
                                               float* __restrict__ dis) {
    __shared__ int s[256];
    int t = threadIdx.x;
    int i = blockIdx.x * 256 + t;
    int v = (i < N_NODES) ? deg[i] : 0;
    if (i < N_NODES) dis[i] = rsqrtf((float)v + 1.0f);  // +1 self-loop
    s[t] = v;
    __syncthreads();
    #pragma unroll
    for (int off = 1; off < 256; off <<= 1) {
        int u = (t >= off) ? s[t - off] : 0;
        __syncthreads();
        s[t] += u;
        __syncthreads();
    }
    if (i < N_NODES) row_ptr[i] = s[t] - v;      // local exclusive
    if (t == 255) partials[blockIdx.x] = s[255]; // block total
}

// level-2: single block scans the 157 partials (exclusive, in place)
__global__ __launch_bounds__(256) void k_scan2(int* __restrict__ partials) {
    __shared__ int s[256];
    int t = threadIdx.x;
    int v = (t < SCAN_NBLK) ? partials[t] : 0;
    s[t] = v;
    __syncthreads();
    #pragma unroll
    for (int off = 1; off < 256; off <<= 1) {
        int u = (t >= off) ? s[t - off] : 0;
        __syncthreads();
        s[t] += u;
        __syncthreads();
    }
    if (t < SCAN_NBLK) partials[t] = s[t] - v;   // exclusive
}

// level-3: add block offsets; row_ptr[N] = E (constant by construction)
__global__ void k_scan3(int* __restrict__ row_ptr, const int* __restrict__ partials) {
    int i = blockIdx.x * blockDim.x + threadIdx.x;
    if (i < N_NODES) row_ptr[i] += partials[blockIdx.x];
    if (i == N_NODES) row_ptr[N_NODES] = N_EDGES;
}

__global__ void k_scatter(const int* __restrict__ tgt, const int* __restrict__ src,
                          const int* __restrict__ row_ptr, int* __restrict__ cnt,
                          const float* __restrict__ dis,
                          int2* __restrict__ ecc) {
    int e = blockIdx.x * blockDim.x + threadIdx.x;
    if (e >= N_EDGES) return;
    int t = tgt[e];
    int s = src[e];
    int pos = row_ptr[t] + atomicAdd(&cnt[t], 1);
    ecc[pos] = make_int2(s, __float_as_int(dis[t] * dis[s]));
}

// ---------------- register-tiled f32 GEMM ----------------
// C[M x Ntot] = concat_k(A0,A1,A2)[M x KTOT] @ W[KTOT x Ntot] (+ bias)
// OUTBF: store bf16 (ushort) instead of f32.
template<int BM, int TM, int KTOT, int NSRC, bool BIAS, bool OUTBF>
__global__ __launch_bounds__(256) void k_gemm_tiled(const float* __restrict__ A0,
                                                    const float* __restrict__ A1,
                                                    const float* __restrict__ A2,
                                                    const float* __restrict__ W,
                                                    const float* __restrict__ bias,
                                                    void* __restrict__ C,
                                                    int Ntot) {
    __shared__ float AT[32][BM + 4];
    __shared__ float Bs[32][64];

    const int t  = threadIdx.x;
    const int tx = t & 15;        // col group: 4 cols each
    const int ty = t >> 4;        // row group: TM rows each
    const int m0 = blockIdx.x * BM;
    const int n0 = blockIdx.y * 64;

    float acc[TM][4];
    #pragma unroll
    for (int i = 0; i < TM; ++i)
        #pragma unroll
        for (int j = 0; j < 4; ++j) acc[i][j] = 0.0f;

    for (int kt = 0; kt < KTOT / 32; ++kt) {
        const float* Ap;
        int kbase;
        if (NSRC == 1) { Ap = A0; kbase = kt * 32; }
        else {
            int s = (kt * 32) >> 7;
            Ap = (s == 0) ? A0 : ((s == 1) ? A1 : A2);
            kbase = (kt * 32) & 127;
        }

        {
            int k0 = (t & 7) * 4;
            for (int rr = t >> 3; rr < BM; rr += 32) {
                int rg = m0 + rr; if (rg > N_NODES - 1) rg = N_NODES - 1;
                const float4 v = *(const float4*)&Ap[(size_t)rg * D + kbase + k0];
                AT[k0 + 0][rr] = v.x;
                AT[k0 + 1][rr] = v.y;
                AT[k0 + 2][rr] = v.z;
                AT[k0 + 3][rr] = v.w;
            }
        }
        {
            int c0 = tx * 4;
            for (int kk = ty; kk < 32; kk += 16)
                *(float4*)&Bs[kk][c0] =
                    *(const float4*)&W[(size_t)(kt * 32 + kk) * Ntot + n0 + c0];
        }
        __syncthreads();

        #pragma unroll
        for (int k = 0; k < 32; ++k) {
            float4 b = *(const float4*)&Bs[k][tx * 4];
            float a[TM];
            {
                const float4 a0 = *(const float4*)&AT[k][ty * TM];
                a[0] = a0.x; a[1] = a0.y; a[2] = a0.z; a[3] = a0.w;
                if (TM == 8) {
                    const float4 a1 = *(const float4*)&AT[k][ty * TM + 4];
                    a[4] = a1.x; a[5] = a1.y; a[6] = a1.z; a[7] = a1.w;
                }
            }
            #pragma unroll
            for (int i = 0; i < TM; ++i) {
                acc[i][0] = fmaf(a[i], b.x, acc[i][0]);
                acc[i][1] = fmaf(a[i], b.y, acc[i][1]);
                acc[i][2] = fmaf(a[i], b.z, acc[i][2]);
                acc[i][3] = fmaf(a[i], b.w, acc[i][3]);
            }
        }
        __syncthreads();
    }

    float4 bb = make_float4(0.f, 0.f, 0.f, 0.f);
    if (BIAS) bb = *(const float4*)&bias[n0 + tx * 4];
    #pragma unroll
    for (int i = 0; i < TM; ++i) {
        int r = m0 + ty * TM + i;
        if (r < N_NODES) {
            if (OUTBF) {
                ushort4 o;
                o.x = f2bf(acc[i][0] + bb.x);
                o.y = f2bf(acc[i][1] + bb.y);
                o.z = f2bf(acc[i][2] + bb.z);
                o.w = f2bf(acc[i][3] + bb.w);
                *(ushort4*)&((unsigned short*)C)[(size_t)r * Ntot + n0 + tx * 4] = o;
            } else {
                float4 o;
                o.x = acc[i][0] + bb.x;
                o.y = acc[i][1] + bb.y;
                o.z = acc[i][2] + bb.z;
                o.w = acc[i][3] + bb.w;
                *(float4*)&((float*)C)[(size_t)r * Ntot + n0 + tx * 4] = o;
            }
        }
    }
}

// ---------------- fused CSR aggregate + bias + self-loop + LayerNorm + ReLU ----
// 2 nodes per wave: each 32-lane half owns one node, lane holds 4 dims (ushort4).
__global__ __launch_bounds__(256) void k_agg_ln(const unsigned short* __restrict__ H,
                                                const float* __restrict__ dis,
                                                const int* __restrict__ row_ptr,
                                                const int2* __restrict__ ecc,
                                                const float* __restrict__ b,
                                                const float* __restrict__ g,
                                                const float* __restrict__ be,
                                                float* __restrict__ OUT) {
    int wv   = threadIdx.x >> 6;
    int lane = threadIdx.x & 63;
    int half = lane >> 5;
    int lh   = lane & 31;
    int i    = blockIdx.x * 8 + wv * 2 + half;
    if (i >= N_NODES) return;

    float a0, a1, a2, a3;
    {
        float  di = dis[i];
        float  c  = di * di;
        ushort4 v = ((const ushort4*)(H + (size_t)i * D))[lh];
        float4 bb = ((const float4*)b)[lh];
        a0 = bb.x + c * bf2f(v.x);
        a1 = bb.y + c * bf2f(v.y);
        a2 = bb.z + c * bf2f(v.z);
        a3 = bb.w + c * bf2f(v.w);
    }

    int e   = row_ptr[i];
    int end = row_ptr[i + 1];
    for (; e + 1 < end; e += 2) {
        int2 p0 = ecc[e];
        int2 p1 = ecc[e + 1];
        ushort4 v0 = ((const ushort4*)(H + (size_t)p0.x * D))[lh];
        ushort4 v1 = ((const ushort4*)(H + (size_t)p1.x * D))[lh];
        float c0 = __int_as_float(p0.y);
        float c1 = __int_as_float(p1.y);
        a0 += c0 * bf2f(v0.x); a1 += c0 * bf2f(v0.y);
        a2 += c0 * bf2f(v0.z); a3 += c0 * bf2f(v0.w);
        a0 += c1 * bf2f(v1.x); a1 += c1 * bf2f(v1.y);
        a2 += c1 * bf2f(v1.z); a3 += c1 * bf2f(v1.w);
    }
    if (e < end) {
        int2 p0 = ecc[e];
        ushort4 v0 = ((const ushort4*)(H + (size_t)p0.x * D))[lh];
        float c0 = __int_as_float(p0.y);
        a0 += c0 * bf2f(v0.x); a1 += c0 * bf2f(v0.y);
        a2 += c0 * bf2f(v0.z); a3 += c0 * bf2f(v0.w);
    }

    // LayerNorm over 128 dims (reduce across the 32-lane half) + ReLU
    float s = a0 + a1 + a2 + a3;
    #pragma unroll
    for (int off = 16; off >= 1; off >>= 1) s += __shfl_xor(s, off);
    float mean = s * (1.0f / 128.0f);

    float d0 = a0 - mean, d1 = a1 - mean, d2 = a2 - mean, d3 = a3 - mean;
    float vs = d0 * d0 + d1 * d1 + d2 * d2 + d3 * d3;
    #pragma unroll
    for (int off = 16; off >= 1; off >>= 1) vs += __shfl_xor(vs, off);
    float inv = rsqrtf(vs * (1.0f / 128.0f) + 1e-5f);

    float4 gg = ((const float4*)g)[lh];
    float4 ee = ((const float4*)be)[lh];
    float4 o;
    o.x = fmaxf(d0 * inv * gg.x + ee.x, 0.0f);
    o.y = fmaxf(d1 * inv * gg.y + ee.y, 0.0f);
    o.z = fmaxf(d2 * inv * gg.z + ee.z, 0.0f);
    o.w = fmaxf(d3 * inv * gg.w + ee.w, 0.0f);
    ((float4*)(OUT + (size_t)i * D))[lh] = o;
}

// ---------------- launcher ----------------
extern "C" void kernel_launch(void* const* d_in, const int* in_sizes, int n_in,
                              void* d_out, int out_size, void* d_ws, size_t ws_size,
                              hipStream_t stream) {
    const float* x   = (const float*)d_in[0];
    const int*   ei  = (const int*)  d_in[1];   // [2, E] int32
    const float* W1  = (const float*)d_in[2];
    const float* b1  = (const float*)d_in[3];
    const float* g1  = (const float*)d_in[4];
    const float* be1 = (const float*)d_in[5];
    const float* W2  = (const float*)d_in[6];
    const float* b2  = (const float*)d_in[7];
    const float* g2  = (const float*)d_in[8];
    const float* be2 = (const float*)d_in[9];
    const float* Wp  = (const float*)d_in[10];
    const float* bp  = (const float*)d_in[11];
    float* out = (float*)d_out;

    const int* tgt = ei;            // edge_index[0] (targets / row)
    const int* src = ei + N_EDGES;  // edge_index[1] (sources / col)

    char* ws = (char*)d_ws;
    int*   deg_i   = (int*)   ws;               ws += 40960 * 4;
    int*   cnt     = (int*)   ws;               ws += 40960 * 4;
    int*   row_ptr = (int*)   ws;               ws += 41984 * 4;
    int*   partials= (int*)   ws;               ws += 256 * 4;
    int2*  ecc     = (int2*)  ws;               ws += (size_t)N_EDGES * 8;
    float* dis     = (float*) ws;               ws += 40960 * 4;
    unsigned short* tmp_bf = (unsigned short*)ws; ws += (size_t)N_NODES * D * 2;
    float* h1      = (float*) ws;               ws += (size_t)N_NODES * D * 4;
    float* h2      = (float*) ws;               ws += (size_t)N_NODES * D * 4;

    const int B = 256;

    // CSR build
    k_zero     <<<(40960 + B - 1) / B, B, 0, stream>>>(deg_i, cnt);
    k_deg_edges<<<(N_EDGES + B - 1) / B, B, 0, stream>>>(tgt, deg_i);
    k_scan1    <<<SCAN_NBLK, B, 0, stream>>>(deg_i, row_ptr, partials, dis);
    k_scan2    <<<1, B, 0, stream>>>(partials);
    k_scan3    <<<SCAN_NBLK + 1, B, 0, stream>>>(row_ptr, partials);
    k_scatter  <<<(N_EDGES + B - 1) / B, B, 0, stream>>>(tgt, src, row_ptr, cnt, dis, ecc);

    // ---- block 1: tmp = bf16(X @ W1) ----
    k_gemm_tiled<128, 8, 128, 1, false, true><<<dim3(313, 2), B, 0, stream>>>(
        x, nullptr, nullptr, W1, nullptr, tmp_bf, 128);
    k_agg_ln   <<<(N_NODES + 7) / 8, B, 0, stream>>>(tmp_bf, dis, row_ptr, ecc, b1, g1, be1, h1);

    // ---- block 2: tmp = bf16(h1 @ W2) ----
    k_gemm_tiled<128, 8, 128, 1, false, true><<<dim3(313, 2), B, 0, stream>>>(
        h1, nullptr, nullptr, W2, nullptr, tmp_bf, 128);
    k_agg_ln   <<<(N_NODES + 7) / 8, B, 0, stream>>>(tmp_bf, dis, row_ptr, ecc, b2, g2, be2, h2);

    // ---- jumping-knowledge concat + projection: out = [x,h1,h2] @ Wp + bp ----
    k_gemm_tiled<64, 4, 384, 3, true, false><<<dim3(625, 1), B, 0, stream>>>(
        x, h1, h2, Wp, bp, out, 64);
}

// Round 6
// 201.853 us; speedup vs baseline: 4.8409x; 1.1190x over previous
//
#include <hip/hip_runtime.h>
#include <math.h>

#define N_NODES 40000
#define N_EDGES 640000
#define D 128
#define D_OUT 64
#define SCAN_NBLK 157   // ceil(40000/256)

typedef __attribute__((ext_vector_type(8))) short short8v;   // 8 bf16 = 4 VGPR
typedef __attribute__((ext_vector_type(4))) float f32x4;

__device__ __forceinline__ float bf2f(unsigned short u) {
    return __uint_as_float(((unsigned int)u) << 16);
}
__device__ __forceinline__ unsigned short f2bf(float f) {
    unsigned int u = __float_as_uint(f);
    return (unsigned short)((u + 0x7FFFu + ((u >> 16) & 1u)) >> 16);  // RNE
}

// ---------------- CSR build ----------------
__global__ void k_zero(int* __restrict__ deg, int* __restrict__ cnt) {
    int i = blockIdx.x * blockDim.x + threadIdx.x;
    if (i < 40960) { deg[i] = 0; cnt[i] = 0; }
}

__global__ void k_deg_edges(const int* __restrict__ tgt, int* __restrict__ deg) {
    int e = blockIdx.x * blockDim.x + threadIdx.x;
    if (e < N_EDGES) atomicAdd(&deg[tgt[e]], 1);
}

__global__ __launch_bounds__(256) void k_scan1(const int* __restrict__ deg,
                                               int* __restrict__ row_ptr,
                                               int* __restrict__ partials,
                                               float* __restrict__ dis) {
    __shared__ int s[256];
    int t = threadIdx.x;
    int i = blockIdx.x * 256 + t;
    int v = (i < N_NODES) ? deg[i] : 0;
    if (i < N_NODES) dis[i] = rsqrtf((float)v + 1.0f);  // +1 self-loop
    s[t] = v;
    __syncthreads();
    #pragma unroll
    for (int off = 1; off < 256; off <<= 1) {
        int u = (t >= off) ? s[t - off] : 0;
        __syncthreads();
        s[t] += u;
        __syncthreads();
    }
    if (i < N_NODES) row_ptr[i] = s[t] - v;
    if (t == 255) partials[blockIdx.x] = s[255];
}

__global__ __launch_bounds__(256) void k_scan2(int* __restrict__ partials) {
    __shared__ int s[256];
    int t = threadIdx.x;
    int v = (t < SCAN_NBLK) ? partials[t] : 0;
    s[t] = v;
    __syncthreads();
    #pragma unroll
    for (int off = 1; off < 256; off <<= 1) {
        int u = (t >= off) ? s[t - off] : 0;
        __syncthreads();
        s[t] += u;
        __syncthreads();
    }
    if (t < SCAN_NBLK) partials[t] = s[t] - v;
}

__global__ void k_scan3(int* __restrict__ row_ptr, const int* __restrict__ partials) {
    int i = blockIdx.x * blockDim.x + threadIdx.x;
    if (i < N_NODES) row_ptr[i] += partials[blockIdx.x];
    if (i == N_NODES) row_ptr[N_NODES] = N_EDGES;
}

__global__ void k_scatter(const int* __restrict__ tgt, const int* __restrict__ src,
                          const int* __restrict__ row_ptr, int* __restrict__ cnt,
                          const float* __restrict__ dis,
                          int2* __restrict__ ecc) {
    int e = blockIdx.x * blockDim.x + threadIdx.x;
    if (e >= N_EDGES) return;
    int t = tgt[e];
    int s = src[e];
    int pos = row_ptr[t] + atomicAdd(&cnt[t], 1);
    ecc[pos] = make_int2(s, __float_as_int(dis[t] * dis[s]));
}

// ---------------- dtype converts ----------------
__global__ void k_cvt_x(const float* __restrict__ X, unsigned short* __restrict__ O, int n4) {
    int i = blockIdx.x * blockDim.x + threadIdx.x;
    if (i < n4) {
        float4 v = ((const float4*)X)[i];
        ushort4 o;
        o.x = f2bf(v.x); o.y = f2bf(v.y); o.z = f2bf(v.z); o.w = f2bf(v.w);
        ((ushort4*)O)[i] = o;
    }
}

// W[K x N] f32 -> Wt[N x K] bf16 (n-major so B-fragments are contiguous)
__global__ void k_cvt_wt(const float* __restrict__ W, unsigned short* __restrict__ Wt,
                         int K, int N) {
    int i = blockIdx.x * blockDim.x + threadIdx.x;  // i = n*K + k
    if (i < K * N) {
        int n = i / K, k = i - n * K;
        Wt[i] = f2bf(W[(size_t)k * N + n]);
    }
}

// ---------------- MFMA GEMM: C_bf16[40000 x 128] = A_bf16 @ W (Wt: [128][128]) --
// 4 waves/block; wave w owns cols [w*32, w*32+32) (2 MFMA n-tiles).
// A fragment: lane l holds row (l&15), k = (l>>4)*8 + j.  B from Wt likewise.
// C: col = lane&15, row = (lane>>4)*4 + r   [m89-verified]
__global__ __launch_bounds__(256) void k_mfma_gemm(const unsigned short* __restrict__ A,
                                                   const unsigned short* __restrict__ Wt,
                                                   unsigned short* __restrict__ C) {
    int w  = threadIdx.x >> 6;
    int l  = threadIdx.x & 63;
    int lr = l & 15;
    int lk = l >> 4;

    short8v wf[2][4];
    #pragma unroll
    for (int nt = 0; nt < 2; ++nt) {
        int n = w * 32 + nt * 16 + lr;
        #pragma unroll
        for (int kc = 0; kc < 4; ++kc)
            wf[nt][kc] = *(const short8v*)(Wt + (size_t)n * 128 + kc * 32 + lk * 8);
    }

    for (int mt = blockIdx.x; mt < 2500; mt += gridDim.x) {
        int m0 = mt * 16;
        f32x4 acc0 = {0.f, 0.f, 0.f, 0.f};
        f32x4 acc1 = {0.f, 0.f, 0.f, 0.f};
        #pragma unroll
        for (int kc = 0; kc < 4; ++kc) {
            short8v a = *(const short8v*)(A + (size_t)(m0 + lr) * 128 + kc * 32 + lk * 8);
            acc0 = __builtin_amdgcn_mfma_f32_16x16x32_bf16(a, wf[0][kc], acc0, 0, 0, 0);
            acc1 = __builtin_amdgcn_mfma_f32_16x16x32_bf16(a, wf[1][kc], acc1, 0, 0, 0);
        }
        int row = m0 + lk * 4;
        int c0  = w * 32 + lr;
        #pragma unroll
        for (int r = 0; r < 4; ++r) {
            C[(size_t)(row + r) * 128 + c0]      = f2bf(acc0[r]);
            C[(size_t)(row + r) * 128 + c0 + 16] = f2bf(acc1[r]);
        }
    }
}

// ---------------- MFMA final: out[40000 x 64] = [x,h1,h2]_bf16 @ Wp + bp ------
__global__ __launch_bounds__(256) void k_mfma_final(const unsigned short* __restrict__ xbf,
                                                    const unsigned short* __restrict__ h1bf,
                                                    const unsigned short* __restrict__ h2bf,
                                                    const unsigned short* __restrict__ Wpt,
                                                    const float* __restrict__ bp,
                                                    float* __restrict__ out) {
    int w  = threadIdx.x >> 6;
    int l  = threadIdx.x & 63;
    int lr = l & 15;
    int lk = l >> 4;

    short8v wf[12];
    {
        int n = w * 16 + lr;
        #pragma unroll
        for (int kc = 0; kc < 12; ++kc)
            wf[kc] = *(const short8v*)(Wpt + (size_t)n * 384 + kc * 32 + lk * 8);
    }
    const unsigned short* srcs[3] = {xbf, h1bf, h2bf};
    float bb = bp[w * 16 + lr];

    for (int mt = blockIdx.x; mt < 2500; mt += gridDim.x) {
        int m0 = mt * 16;
        f32x4 acc = {0.f, 0.f, 0.f, 0.f};
        #pragma unroll
        for (int kc = 0; kc < 12; ++kc) {
            const unsigned short* S = srcs[kc >> 2];
            short8v a = *(const short8v*)(S + (size_t)(m0 + lr) * 128 + (kc & 3) * 32 + lk * 8);
            acc = __builtin_amdgcn_mfma_f32_16x16x32_bf16(a, wf[kc], acc, 0, 0, 0);
        }
        int row = m0 + lk * 4;
        int c   = w * 16 + lr;
        #pragma unroll
        for (int r = 0; r < 4; ++r)
            out[(size_t)(row + r) * 64 + c] = acc[r] + bb;
    }
}

// ---------------- fused CSR aggregate + bias + self-loop + LayerNorm + ReLU ----
// 2 nodes per wave; lane holds 4 dims (ushort4 = 8B load). Output bf16.
__global__ __launch_bounds__(256) void k_agg_ln(const unsigned short* __restrict__ H,
                                                const float* __restrict__ dis,
                                                const int* __restrict__ row_ptr,
                                                const int2* __restrict__ ecc,
                                                const float* __restrict__ b,
                                                const float* __restrict__ g,
                                                const float* __restrict__ be,
                                                unsigned short* __restrict__ OUT) {
    int wv   = threadIdx.x >> 6;
    int lane = threadIdx.x & 63;
    int half = lane >> 5;
    int lh   = lane & 31;
    int i    = blockIdx.x * 8 + wv * 2 + half;
    if (i >= N_NODES) return;

    float a0, a1, a2, a3;
    {
        float  di = dis[i];
        float  c  = di * di;
        ushort4 v = ((const ushort4*)(H + (size_t)i * D))[lh];
        float4 bb = ((const float4*)b)[lh];
        a0 = bb.x + c * bf2f(v.x);
        a1 = bb.y + c * bf2f(v.y);
        a2 = bb.z + c * bf2f(v.z);
        a3 = bb.w + c * bf2f(v.w);
    }

    int e   = row_ptr[i];
    int end = row_ptr[i + 1];
    for (; e + 1 < end; e += 2) {
        int2 p0 = ecc[e];
        int2 p1 = ecc[e + 1];
        ushort4 v0 = ((const ushort4*)(H + (size_t)p0.x * D))[lh];
        ushort4 v1 = ((const ushort4*)(H + (size_t)p1.x * D))[lh];
        float c0 = __int_as_float(p0.y);
        float c1 = __int_as_float(p1.y);
        a0 += c0 * bf2f(v0.x); a1 += c0 * bf2f(v0.y);
        a2 += c0 * bf2f(v0.z); a3 += c0 * bf2f(v0.w);
        a0 += c1 * bf2f(v1.x); a1 += c1 * bf2f(v1.y);
        a2 += c1 * bf2f(v1.z); a3 += c1 * bf2f(v1.w);
    }
    if (e < end) {
        int2 p0 = ecc[e];
        ushort4 v0 = ((const ushort4*)(H + (size_t)p0.x * D))[lh];
        float c0 = __int_as_float(p0.y);
        a0 += c0 * bf2f(v0.x); a1 += c0 * bf2f(v0.y);
        a2 += c0 * bf2f(v0.z); a3 += c0 * bf2f(v0.w);
    }

    float s = a0 + a1 + a2 + a3;
    #pragma unroll
    for (int off = 16; off >= 1; off >>= 1) s += __shfl_xor(s, off);
    float mean = s * (1.0f / 128.0f);

    float d0 = a0 - mean, d1 = a1 - mean, d2 = a2 - mean, d3 = a3 - mean;
    float vs = d0 * d0 + d1 * d1 + d2 * d2 + d3 * d3;
    #pragma unroll
    for (int off = 16; off >= 1; off >>= 1) vs += __shfl_xor(vs, off);
    float inv = rsqrtf(vs * (1.0f / 128.0f) + 1e-5f);

    float4 gg = ((const float4*)g)[lh];
    float4 ee = ((const float4*)be)[lh];
    ushort4 o;
    o.x = f2bf(fmaxf(d0 * inv * gg.x + ee.x, 0.0f));
    o.y = f2bf(fmaxf(d1 * inv * gg.y + ee.y, 0.0f));
    o.z = f2bf(fmaxf(d2 * inv * gg.z + ee.z, 0.0f));
    o.w = f2bf(fmaxf(d3 * inv * gg.w + ee.w, 0.0f));
    ((ushort4*)(OUT + (size_t)i * D))[lh] = o;
}

// ---------------- launcher ----------------
extern "C" void kernel_launch(void* const* d_in, const int* in_sizes, int n_in,
                              void* d_out, int out_size, void* d_ws, size_t ws_size,
                              hipStream_t stream) {
    const float* x   = (const float*)d_in[0];
    const int*   ei  = (const int*)  d_in[1];   // [2, E] int32
    const float* W1  = (const float*)d_in[2];
    const float* b1  = (const float*)d_in[3];
    const float* g1  = (const float*)d_in[4];
    const float* be1 = (const float*)d_in[5];
    const float* W2  = (const float*)d_in[6];
    const float* b2  = (const float*)d_in[7];
    const float* g2  = (const float*)d_in[8];
    const float* be2 = (const float*)d_in[9];
    const float* Wp  = (const float*)d_in[10];
    const float* bp  = (const float*)d_in[11];
    float* out = (float*)d_out;

    const int* tgt = ei;
    const int* src = ei + N_EDGES;

    char* ws = (char*)d_ws;
    int*   deg_i   = (int*)   ws;               ws += 40960 * 4;
    int*   cnt     = (int*)   ws;               ws += 40960 * 4;
    int*   row_ptr = (int*)   ws;               ws += 41984 * 4;
    int*   partials= (int*)   ws;               ws += 256 * 4;
    int2*  ecc     = (int2*)  ws;               ws += (size_t)N_EDGES * 8;
    float* dis     = (float*) ws;               ws += 40960 * 4;
    unsigned short* x_bf   = (unsigned short*)ws; ws += (size_t)N_NODES * D * 2;
    unsigned short* tmp_bf = (unsigned short*)ws; ws += (size_t)N_NODES * D * 2;
    unsigned short* h1_bf  = (unsigned short*)ws; ws += (size_t)N_NODES * D * 2;
    unsigned short* h2_bf  = (unsigned short*)ws; ws += (size_t)N_NODES * D * 2;
    unsigned short* W1t    = (unsigned short*)ws; ws += 128 * 128 * 2;
    unsigned short* W2t    = (unsigned short*)ws; ws += 128 * 128 * 2;
    unsigned short* Wpt    = (unsigned short*)ws; ws += 384 * 64 * 2;

    const int B = 256;

    // CSR build
    k_zero     <<<(40960 + B - 1) / B, B, 0, stream>>>(deg_i, cnt);
    k_deg_edges<<<(N_EDGES + B - 1) / B, B, 0, stream>>>(tgt, deg_i);
    k_scan1    <<<SCAN_NBLK, B, 0, stream>>>(deg_i, row_ptr, partials, dis);
    k_scan2    <<<1, B, 0, stream>>>(partials);
    k_scan3    <<<SCAN_NBLK, B, 0, stream>>>(row_ptr, partials);
    k_scatter  <<<(N_EDGES + B - 1) / B, B, 0, stream>>>(tgt, src, row_ptr, cnt, dis, ecc);

    // dtype converts
    k_cvt_x    <<<(N_NODES * D / 4 + B - 1) / B, B, 0, stream>>>(x, x_bf, N_NODES * D / 4);
    k_cvt_wt   <<<(128 * 128 + B - 1) / B, B, 0, stream>>>(W1, W1t, 128, 128);
    k_cvt_wt   <<<(128 * 128 + B - 1) / B, B, 0, stream>>>(W2, W2t, 128, 128);
    k_cvt_wt   <<<(384 * 64  + B - 1) / B, B, 0, stream>>>(Wp, Wpt, 384, 64);

    // ---- block 1 ----
    k_mfma_gemm<<<1250, B, 0, stream>>>(x_bf, W1t, tmp_bf);
    k_agg_ln   <<<(N_NODES + 7) / 8, B, 0, stream>>>(tmp_bf, dis, row_ptr, ecc, b1, g1, be1, h1_bf);

    // ---- block 2 ----
    k_mfma_gemm<<<1250, B, 0, stream>>>(h1_bf, W2t, tmp_bf);
    k_agg_ln   <<<(N_NODES + 7) / 8, B, 0, stream>>>(tmp_bf, dis, row_ptr, ecc, b2, g2, be2, h2_bf);

    // ---- jumping-knowledge concat + projection ----
    k_mfma_final<<<1250, B, 0, stream>>>(x_bf, h1_bf, h2_bf, Wpt, bp, out);
}

// Round 7
// 183.582 us; speedup vs baseline: 5.3227x; 1.0995x over previous
//
#include <hip/hip_runtime.h>
#include <math.h>

#define N_NODES 40000
#define N_EDGES 640000
#define D 128
#define D_OUT 64
#define SCAN_NBLK 157   // ceil(40000/256)

typedef __attribute__((ext_vector_type(8))) short short8v;   // 8 bf16 = 4 VGPR
typedef __attribute__((ext_vector_type(8))) unsigned short ushort8v;
typedef __attribute__((ext_vector_type(4))) float f32x4;

__device__ __forceinline__ float bf2f(unsigned short u) {
    return __uint_as_float(((unsigned int)u) << 16);
}
__device__ __forceinline__ unsigned short f2bf(float f) {
    unsigned int u = __float_as_uint(f);
    return (unsigned short)((u + 0x7FFFu + ((u >> 16) & 1u)) >> 16);  // RNE
}

// ---------------- fused prep: zero counters + bf16 converts + W transposes ----
__global__ __launch_bounds__(256) void k_prep(const float* __restrict__ X,
                                              const float* __restrict__ W1,
                                              const float* __restrict__ W2,
                                              const float* __restrict__ Wp,
                                              int* __restrict__ deg, int* __restrict__ cnt,
                                              unsigned short* __restrict__ x_bf,
                                              unsigned short* __restrict__ W1t,
                                              unsigned short* __restrict__ W2t,
                                              unsigned short* __restrict__ Wpt) {
    int i = blockIdx.x * 256 + threadIdx.x;   // grid = 5000 blocks = 1.28M threads
    if (i < 40960) { deg[i] = 0; cnt[i] = 0; }
    if (i < 128 * 128) {            // Wt[n*K+k] = W[k*N+n]
        int n = i >> 7, k = i & 127;
        W1t[i] = f2bf(W1[(size_t)k * 128 + n]);
        W2t[i] = f2bf(W2[(size_t)k * 128 + n]);
    }
    if (i < 384 * 64) {
        int n = i / 384, k = i - n * 384;
        Wpt[i] = f2bf(Wp[(size_t)k * 64 + n]);
    }
    if (i < N_NODES * D / 4) {
        float4 v = ((const float4*)X)[i];
        ushort4 o;
        o.x = f2bf(v.x); o.y = f2bf(v.y); o.z = f2bf(v.z); o.w = f2bf(v.w);
        ((ushort4*)x_bf)[i] = o;
    }
}

// ---------------- CSR build ----------------
__global__ void k_deg_edges(const int* __restrict__ tgt, int* __restrict__ deg) {
    int e = blockIdx.x * blockDim.x + threadIdx.x;
    if (e < N_EDGES) atomicAdd(&deg[tgt[e]], 1);
}

__global__ __launch_bounds__(256) void k_scan1(const int* __restrict__ deg,
                                               int* __restrict__ row_ptr,
                                               int* __restrict__ partials,
                                               float* __restrict__ dis) {
    __shared__ int s[256];
    int t = threadIdx.x;
    int i = blockIdx.x * 256 + t;
    int v = (i < N_NODES) ? deg[i] : 0;
    if (i < N_NODES) dis[i] = rsqrtf((float)v + 1.0f);  // +1 self-loop
    s[t] = v;
    __syncthreads();
    #pragma unroll
    for (int off = 1; off < 256; off <<= 1) {
        int u = (t >= off) ? s[t - off] : 0;
        __syncthreads();
        s[t] += u;
        __syncthreads();
    }
    if (i < N_NODES) row_ptr[i] = s[t] - v;
    if (t == 255) partials[blockIdx.x] = s[255];
}

__global__ __launch_bounds__(256) void k_scan2(int* __restrict__ partials) {
    __shared__ int s[256];
    int t = threadIdx.x;
    int v = (t < SCAN_NBLK) ? partials[t] : 0;
    s[t] = v;
    __syncthreads();
    #pragma unroll
    for (int off = 1; off < 256; off <<= 1) {
        int u = (t >= off) ? s[t - off] : 0;
        __syncthreads();
        s[t] += u;
        __syncthreads();
    }
    if (t < SCAN_NBLK) partials[t] = s[t] - v;
}

__global__ void k_scan3(int* __restrict__ row_ptr, const int* __restrict__ partials) {
    int i = blockIdx.x * blockDim.x + threadIdx.x;
    if (i < N_NODES) row_ptr[i] += partials[blockIdx.x];
    if (i == 0) row_ptr[N_NODES] = N_EDGES;
}

__global__ void k_scatter(const int* __restrict__ tgt, const int* __restrict__ src,
                          const int* __restrict__ row_ptr, int* __restrict__ cnt,
                          const float* __restrict__ dis,
                          int2* __restrict__ ecc) {
    int e = blockIdx.x * blockDim.x + threadIdx.x;
    if (e >= N_EDGES) return;
    int t = tgt[e];
    int s = src[e];
    int pos = row_ptr[t] + atomicAdd(&cnt[t], 1);
    ecc[pos] = make_int2(s, __float_as_int(dis[t] * dis[s]));
}

// ---------------- MFMA GEMM: C_bf16[40000 x 128] = A_bf16 @ W (Wt: [128][128]) --
__global__ __launch_bounds__(256) void k_mfma_gemm(const unsigned short* __restrict__ A,
                                                   const unsigned short* __restrict__ Wt,
                                                   unsigned short* __restrict__ C) {
    int w  = threadIdx.x >> 6;
    int l  = threadIdx.x & 63;
    int lr = l & 15;
    int lk = l >> 4;

    short8v wf[2][4];
    #pragma unroll
    for (int nt = 0; nt < 2; ++nt) {
        int n = w * 32 + nt * 16 + lr;
        #pragma unroll
        for (int kc = 0; kc < 4; ++kc)
            wf[nt][kc] = *(const short8v*)(Wt + (size_t)n * 128 + kc * 32 + lk * 8);
    }

    for (int mt = blockIdx.x; mt < 2500; mt += gridDim.x) {
        int m0 = mt * 16;
        f32x4 acc0 = {0.f, 0.f, 0.f, 0.f};
        f32x4 acc1 = {0.f, 0.f, 0.f, 0.f};
        #pragma unroll
        for (int kc = 0; kc < 4; ++kc) {
            short8v a = *(const short8v*)(A + (size_t)(m0 + lr) * 128 + kc * 32 + lk * 8);
            acc0 = __builtin_amdgcn_mfma_f32_16x16x32_bf16(a, wf[0][kc], acc0, 0, 0, 0);
            acc1 = __builtin_amdgcn_mfma_f32_16x16x32_bf16(a, wf[1][kc], acc1, 0, 0, 0);
        }
        int row = m0 + lk * 4;
        int c0  = w * 32 + lr;
        #pragma unroll
        for (int r = 0; r < 4; ++r) {
            C[(size_t)(row + r) * 128 + c0]      = f2bf(acc0[r]);
            C[(size_t)(row + r) * 128 + c0 + 16] = f2bf(acc1[r]);
        }
    }
}

// ---------------- MFMA final: out[40000 x 64] = [x,h1,h2]_bf16 @ Wp + bp ------
__global__ __launch_bounds__(256) void k_mfma_final(const unsigned short* __restrict__ xbf,
                                                    const unsigned short* __restrict__ h1bf,
                                                    const unsigned short* __restrict__ h2bf,
                                                    const unsigned short* __restrict__ Wpt,
                                                    const float* __restrict__ bp,
                                                    float* __restrict__ out) {
    int w  = threadIdx.x >> 6;
    int l  = threadIdx.x & 63;
    int lr = l & 15;
    int lk = l >> 4;

    short8v wf[12];
    {
        int n = w * 16 + lr;
        #pragma unroll
        for (int kc = 0; kc < 12; ++kc)
            wf[kc] = *(const short8v*)(Wpt + (size_t)n * 384 + kc * 32 + lk * 8);
    }
    const unsigned short* srcs[3] = {xbf, h1bf, h2bf};
    float bb = bp[w * 16 + lr];

    for (int mt = blockIdx.x; mt < 2500; mt += gridDim.x) {
        int m0 = mt * 16;
        f32x4 acc = {0.f, 0.f, 0.f, 0.f};
        #pragma unroll
        for (int kc = 0; kc < 12; ++kc) {
            const unsigned short* S = srcs[kc >> 2];
            short8v a = *(const short8v*)(S + (size_t)(m0 + lr) * 128 + (kc & 3) * 32 + lk * 8);
            acc = __builtin_amdgcn_mfma_f32_16x16x32_bf16(a, wf[kc], acc, 0, 0, 0);
        }
        int row = m0 + lk * 4;
        int c   = w * 16 + lr;
        #pragma unroll
        for (int r = 0; r < 4; ++r)
            out[(size_t)(row + r) * 64 + c] = acc[r] + bb;
    }
}

// ---------------- fused CSR aggregate + bias + self-loop + LayerNorm + ReLU ----
// 4 nodes per wave: 16 lanes per node, lane holds 8 dims (ushort8 = 16B load).
__global__ __launch_bounds__(256) void k_agg_ln(const unsigned short* __restrict__ H,
                                                const float* __restrict__ dis,
                                                const int* __restrict__ row_ptr,
                                                const int2* __restrict__ ecc,
                                                const float* __restrict__ b,
                                                const float* __restrict__ g,
                                                const float* __restrict__ be,
                                                unsigned short* __restrict__ OUT) {
    int lane = threadIdx.x & 63;
    int lh   = lane & 15;                       // dim group: 8 dims
    int i    = blockIdx.x * 16 + ((threadIdx.x >> 4) & ~0u);  // 16 nodes/block
    i = blockIdx.x * 16 + (threadIdx.x >> 4);
    if (i >= N_NODES) return;

    float a[8];
    {
        float   di = dis[i];
        float   c  = di * di;
        ushort8v v = *(const ushort8v*)(H + (size_t)i * D + lh * 8);
        const float4* b4 = (const float4*)(b + lh * 8);
        float4 bb0 = b4[0], bb1 = b4[1];
        a[0] = bb0.x + c * bf2f(v[0]); a[1] = bb0.y + c * bf2f(v[1]);
        a[2] = bb0.z + c * bf2f(v[2]); a[3] = bb0.w + c * bf2f(v[3]);
        a[4] = bb1.x + c * bf2f(v[4]); a[5] = bb1.y + c * bf2f(v[5]);
        a[6] = bb1.z + c * bf2f(v[6]); a[7] = bb1.w + c * bf2f(v[7]);
    }

    int e   = row_ptr[i];
    int end = row_ptr[i + 1];
    if ((e & 1) && e < end) {                   // peel to 16B-align ecc reads
        int2 p = ecc[e];
        float c0 = __int_as_float(p.y);
        ushort8v v = *(const ushort8v*)(H + (size_t)p.x * D + lh * 8);
        #pragma unroll
        for (int j = 0; j < 8; ++j) a[j] += c0 * bf2f(v[j]);
        ++e;
    }
    for (; e + 1 < end; e += 2) {
        int4 p = *(const int4*)&ecc[e];         // 2 edge records, one 16B load
        ushort8v v0 = *(const ushort8v*)(H + (size_t)p.x * D + lh * 8);
        ushort8v v1 = *(const ushort8v*)(H + (size_t)p.z * D + lh * 8);
        float c0 = __int_as_float(p.y);
        float c1 = __int_as_float(p.w);
        #pragma unroll
        for (int j = 0; j < 8; ++j) a[j] += c0 * bf2f(v0[j]);
        #pragma unroll
        for (int j = 0; j < 8; ++j) a[j] += c1 * bf2f(v1[j]);
    }
    if (e < end) {
        int2 p = ecc[e];
        float c0 = __int_as_float(p.y);
        ushort8v v = *(const ushort8v*)(H + (size_t)p.x * D + lh * 8);
        #pragma unroll
        for (int j = 0; j < 8; ++j) a[j] += c0 * bf2f(v[j]);
    }

    // LayerNorm over 128 dims: 8 local + reduce across 16 lanes
    float s = 0.f;
    #pragma unroll
    for (int j = 0; j < 8; ++j) s += a[j];
    #pragma unroll
    for (int off = 8; off >= 1; off >>= 1) s += __shfl_xor(s, off);
    float mean = s * (1.0f / 128.0f);

    float vs = 0.f;
    #pragma unroll
    for (int j = 0; j < 8; ++j) { a[j] -= mean; vs += a[j] * a[j]; }
    #pragma unroll
    for (int off = 8; off >= 1; off >>= 1) vs += __shfl_xor(vs, off);
    float inv = rsqrtf(vs * (1.0f / 128.0f) + 1e-5f);

    const float4* g4 = (const float4*)(g + lh * 8);
    const float4* e4 = (const float4*)(be + lh * 8);
    float4 g0 = g4[0], g1 = g4[1], e0 = e4[0], e1 = e4[1];
    ushort8v o;
    o[0] = f2bf(fmaxf(a[0] * inv * g0.x + e0.x, 0.0f));
    o[1] = f2bf(fmaxf(a[1] * inv * g0.y + e0.y, 0.0f));
    o[2] = f2bf(fmaxf(a[2] * inv * g0.z + e0.z, 0.0f));
    o[3] = f2bf(fmaxf(a[3] * inv * g0.w + e0.w, 0.0f));
    o[4] = f2bf(fmaxf(a[4] * inv * g1.x + e1.x, 0.0f));
    o[5] = f2bf(fmaxf(a[5] * inv * g1.y + e1.y, 0.0f));
    o[6] = f2bf(fmaxf(a[6] * inv * g1.z + e1.z, 0.0f));
    o[7] = f2bf(fmaxf(a[7] * inv * g1.w + e1.w, 0.0f));
    *(ushort8v*)(OUT + (size_t)i * D + lh * 8) = o;
}

// ---------------- launcher ----------------
extern "C" void kernel_launch(void* const* d_in, const int* in_sizes, int n_in,
                              void* d_out, int out_size, void* d_ws, size_t ws_size,
                              hipStream_t stream) {
    const float* x   = (const float*)d_in[0];
    const int*   ei  = (const int*)  d_in[1];   // [2, E] int32
    const float* W1  = (const float*)d_in[2];
    const float* b1  = (const float*)d_in[3];
    const float* g1  = (const float*)d_in[4];
    const float* be1 = (const float*)d_in[5];
    const float* W2  = (const float*)d_in[6];
    const float* b2  = (const float*)d_in[7];
    const float* g2  = (const float*)d_in[8];
    const float* be2 = (const float*)d_in[9];
    const float* Wp  = (const float*)d_in[10];
    const float* bp  = (const float*)d_in[11];
    float* out = (float*)d_out;

    const int* tgt = ei;
    const int* src = ei + N_EDGES;

    char* ws = (char*)d_ws;
    int*   deg_i   = (int*)   ws;               ws += 40960 * 4;
    int*   cnt     = (int*)   ws;               ws += 40960 * 4;
    int*   row_ptr = (int*)   ws;               ws += 41984 * 4;
    int*   partials= (int*)   ws;               ws += 256 * 4;
    int2*  ecc     = (int2*)  ws;               ws += (size_t)N_EDGES * 8;
    float* dis     = (float*) ws;               ws += 40960 * 4;
    unsigned short* x_bf   = (unsigned short*)ws; ws += (size_t)N_NODES * D * 2;
    unsigned short* tmp_bf = (unsigned short*)ws; ws += (size_t)N_NODES * D * 2;
    unsigned short* h1_bf  = (unsigned short*)ws; ws += (size_t)N_NODES * D * 2;
    unsigned short* h2_bf  = (unsigned short*)ws; ws += (size_t)N_NODES * D * 2;
    unsigned short* W1t    = (unsigned short*)ws; ws += 128 * 128 * 2;
    unsigned short* W2t    = (unsigned short*)ws; ws += 128 * 128 * 2;
    unsigned short* Wpt    = (unsigned short*)ws; ws += 384 * 64 * 2;

    const int B = 256;

    // prep (zero + converts) and CSR build
    k_prep     <<<5000, B, 0, stream>>>(x, W1, W2, Wp, deg_i, cnt, x_bf, W1t, W2t, Wpt);
    k_deg_edges<<<(N_EDGES + B - 1) / B, B, 0, stream>>>(tgt, deg_i);
    k_scan1    <<<SCAN_NBLK, B, 0, stream>>>(deg_i, row_ptr, partials, dis);
    k_scan2    <<<1, B, 0, stream>>>(partials);
    k_scan3    <<<SCAN_NBLK, B, 0, stream>>>(row_ptr, partials);
    k_scatter  <<<(N_EDGES + B - 1) / B, B, 0, stream>>>(tgt, src, row_ptr, cnt, dis, ecc);

    // ---- block 1 ----
    k_mfma_gemm<<<1250, B, 0, stream>>>(x_bf, W1t, tmp_bf);
    k_agg_ln   <<<2500, B, 0, stream>>>(tmp_bf, dis, row_ptr, ecc, b1, g1, be1, h1_bf);

    // ---- block 2 ----
    k_mfma_gemm<<<1250, B, 0, stream>>>(h1_bf, W2t, tmp_bf);
    k_agg_ln   <<<2500, B, 0, stream>>>(tmp_bf, dis, row_ptr, ecc, b2, g2, be2, h2_bf);

    // ---- jumping-knowledge concat + projection ----
    k_mfma_final<<<1250, B, 0, stream>>>(x_bf, h1_bf, h2_bf, Wpt, bp, out);
}